// Round 8
// baseline (198.474 us; speedup 1.0000x reference)
//
#include <hip/hip_runtime.h>

#define BATCH 32
#define H 512
#define W 512
#define SEG 8                       // output rows per block
#define TPB 64                      // ONE wave per block: no barriers, no LDS
// final scalar = sum over pixels of ((1-cc1)+(1-cc2)) * 0.5 / (B*H*W)
#define SCALE (0.5f / 8388608.0f)

typedef float f32x4 __attribute__((ext_vector_type(4)));

// __launch_bounds__(64,4): cap VGPR at 128 so 4 waves/SIMD fit; live-set is
// structured to ~100 regs so this must not spill (WRITE_SIZE is the canary).
__global__ __launch_bounds__(TPB, 4) void ncc_loss_kernel(
    const float* __restrict__ g1, const float* __restrict__ g2,
    const float* __restrict__ gf, float* __restrict__ out)
{
    const int lane = threadIdx.x;                    // owns 4 cols
    const int bx   = blockIdx.x;                     // 256-col tile (0 or 1)
    const int voff = bx * 1024 + 16 * lane;          // own x4 byte offset in row
    const int y0   = blockIdx.y * SEG;
    const int b    = blockIdx.z;
    const size_t base = (size_t)b * (H * W);

    // left-halo load: lane 0 of tile 0 would be voffset -16 (unsigned wrap ->
    // bounds check unreliable) -> clamp to 0 and zero the quarter after load.
    const bool e0  = (bx == 0) & (lane == 0);
    const int voL  = e0 ? 0 : (voff - 16);
    // right halo voff+16: tile1/lane63 gives 2048 = num_records -> OOB -> 0. OK.

    // vertical running sums, 8 quantities x 4 columns (64 VGPRs total... 32)
    float v1[4], v2[4], vf[4], v11[4], v22[4], vff[4], v1f[4], v2f[4];
#pragma unroll
    for (int c = 0; c < 4; ++c) {
        v1[c]=0.f; v2[c]=0.f; vf[c]=0.f; v11[c]=0.f;
        v22[c]=0.f; vff[c]=0.f; v1f[c]=0.f; v2f[c]=0.f;
    }
    float lsum = 0.f;
    const float inv_n = 1.0f / 81.0f;

    // 4 sliding 9-window sums from 12 raw values (3 f32x4 quarters)
    auto hwin = [](f32x4 L, f32x4 M, f32x4 R, float* h) {
        float s = (L[0]+L[1]) + (L[2]+L[3]) + ((M[0]+M[1]) + (M[2]+M[3])) + R[0];
        h[0]=s; s += R[1]-L[0]; h[1]=s; s += R[2]-L[1]; h[2]=s; s += R[3]-L[2]; h[3]=s;
    };
    // same for elementwise products U*W
    auto hwinp = [](f32x4 UL, f32x4 UM, f32x4 UR,
                    f32x4 WL, f32x4 WM, f32x4 WR, float* h) {
        const float p0 = UL[0]*WL[0], p1 = UL[1]*WL[1], p2 = UL[2]*WL[2];
        float s = p0 + p1 + p2;
        s = fmaf(UL[3], WL[3], s);
        s = fmaf(UM[0], WM[0], s); s = fmaf(UM[1], WM[1], s);
        s = fmaf(UM[2], WM[2], s); s = fmaf(UM[3], WM[3], s);
        s = fmaf(UR[0], WR[0], s);
        h[0]=s;
        s = fmaf(UR[1], WR[1], s) - p0; h[1]=s;
        s = fmaf(UR[2], WR[2], s) - p1; h[2]=s;
        s = fmaf(UR[3], WR[3], s) - p2; h[3]=s;
    };

    // visit one raw row: 9 b128 loads, 8 horizontal window sums, v-update.
    // sg=+1: enter, sg=-1: leave. Leave recomputes bitwise-identical h-sums
    // from identical loads -> exact cancellation (validated: absmax 0).
    auto visit = [&](int yr, float sg) {
        const int rec = ((unsigned)yr < (unsigned)H) ? (W * 4) : 0;  // v-pad
        const int yc  = yr < 0 ? 0 : (yr >= H ? H - 1 : yr);
        const size_t roff = base + (size_t)yc * W;
        __amdgpu_buffer_rsrc_t ra = __builtin_amdgcn_make_buffer_rsrc(
            (void*)(g1 + roff), (short)0, rec, 0x00020000);
        __amdgpu_buffer_rsrc_t rc = __builtin_amdgcn_make_buffer_rsrc(
            (void*)(g2 + roff), (short)0, rec, 0x00020000);
        __amdgpu_buffer_rsrc_t rv = __builtin_amdgcn_make_buffer_rsrc(
            (void*)(gf + roff), (short)0, rec, 0x00020000);

        // all 9 loads issued up front (independent, vmcnt-overlapped)
        f32x4 A0 = __builtin_bit_cast(f32x4, __builtin_amdgcn_raw_buffer_load_b128(ra, voL,     0, 0));
        f32x4 A1 = __builtin_bit_cast(f32x4, __builtin_amdgcn_raw_buffer_load_b128(ra, voff,    0, 0));
        f32x4 A2 = __builtin_bit_cast(f32x4, __builtin_amdgcn_raw_buffer_load_b128(ra, voff+16, 0, 0));
        f32x4 C0 = __builtin_bit_cast(f32x4, __builtin_amdgcn_raw_buffer_load_b128(rc, voL,     0, 0));
        f32x4 C1 = __builtin_bit_cast(f32x4, __builtin_amdgcn_raw_buffer_load_b128(rc, voff,    0, 0));
        f32x4 C2 = __builtin_bit_cast(f32x4, __builtin_amdgcn_raw_buffer_load_b128(rc, voff+16, 0, 0));
        f32x4 F0 = __builtin_bit_cast(f32x4, __builtin_amdgcn_raw_buffer_load_b128(rv, voL,     0, 0));
        f32x4 F1 = __builtin_bit_cast(f32x4, __builtin_amdgcn_raw_buffer_load_b128(rv, voff,    0, 0));
        f32x4 F2 = __builtin_bit_cast(f32x4, __builtin_amdgcn_raw_buffer_load_b128(rv, voff+16, 0, 0));
        if (e0) { A0 = 0.f; C0 = 0.f; F0 = 0.f; }    // true left-edge zeros

        float h[4];
        hwin(F0, F1, F2, h);
#pragma unroll
        for (int c = 0; c < 4; ++c) vf[c]  = fmaf(sg, h[c], vf[c]);
        hwinp(F0, F1, F2, F0, F1, F2, h);
#pragma unroll
        for (int c = 0; c < 4; ++c) vff[c] = fmaf(sg, h[c], vff[c]);
        hwin(A0, A1, A2, h);
#pragma unroll
        for (int c = 0; c < 4; ++c) v1[c]  = fmaf(sg, h[c], v1[c]);
        hwinp(A0, A1, A2, A0, A1, A2, h);
#pragma unroll
        for (int c = 0; c < 4; ++c) v11[c] = fmaf(sg, h[c], v11[c]);
        hwinp(A0, A1, A2, F0, F1, F2, h);
#pragma unroll
        for (int c = 0; c < 4; ++c) v1f[c] = fmaf(sg, h[c], v1f[c]);
        hwin(C0, C1, C2, h);
#pragma unroll
        for (int c = 0; c < 4; ++c) v2[c]  = fmaf(sg, h[c], v2[c]);
        hwinp(C0, C1, C2, C0, C1, C2, h);
#pragma unroll
        for (int c = 0; c < 4; ++c) v22[c] = fmaf(sg, h[c], v22[c]);
        hwinp(C0, C1, C2, F0, F1, F2, h);
#pragma unroll
        for (int c = 0; c < 4; ++c) v2f[c] = fmaf(sg, h[c], v2f[c]);
    };

    auto emit = [&]() {
#pragma unroll
        for (int c = 0; c < 4; ++c) {
            const float u1 = v1[c]*inv_n, u2 = v2[c]*inv_n, uf = vf[c]*inv_n;
            const float cross1 = fmaf(-v1[c], uf, v1f[c]);
            const float var1   = fmaf(-v1[c], u1, v11[c]);
            const float varf   = fmaf(-vf[c], uf, vff[c]);
            const float cross2 = fmaf(-v2[c], uf, v2f[c]);
            const float var2   = fmaf(-v2[c], u2, v22[c]);
            const float d1 = fmaf(var1, varf, 1e-5f);
            const float d2 = fmaf(var2, varf, 1e-5f);
            // cc1 + cc2 = (cross1^2*d2 + cross2^2*d1) / (d1*d2): one rcp
            const float inv = __builtin_amdgcn_rcpf(d1 * d2);
            float num = cross1 * cross1 * d2;
            num = fmaf(cross2 * cross2, d1, num);
            lsum += fmaf(-num, inv, 2.0f);           // (1-cc1)+(1-cc2)
        }
    };

    // prologue: rows y0-4 .. y0+4 -> window for output row y0
#pragma unroll 1
    for (int s = 0; s < 9; ++s) visit(y0 - 4 + s, 1.0f);
    emit();
    // steady state: enter next row, leave oldest row, emit
#pragma unroll 1
    for (int j = 1; j < SEG; ++j) {
        visit(y0 + 4 + j, 1.0f);
        visit(y0 - 5 + j, -1.0f);
        emit();
    }

    // single-wave block: shuffle reduce + one atomic. No LDS, no barriers.
#pragma unroll
    for (int o = 32; o > 0; o >>= 1)
        lsum += __shfl_down(lsum, o, 64);
    if (lane == 0) atomicAdd(out, lsum * SCALE);
}

extern "C" void kernel_launch(void* const* d_in, const int* in_sizes, int n_in,
                              void* d_out, int out_size, void* d_ws, size_t ws_size,
                              hipStream_t stream) {
    const float* img1 = (const float*)d_in[0];
    const float* img2 = (const float*)d_in[1];
    const float* fimg = (const float*)d_in[2];
    float* out = (float*)d_out;

    hipMemsetAsync(out, 0, sizeof(float), stream);  // d_out re-poisoned each call

    dim3 grid(2, H / SEG, BATCH);   // (2, 64, 32) = 4096 single-wave blocks
    ncc_loss_kernel<<<grid, dim3(TPB), 0, stream>>>(img1, img2, fimg, out);
}

// Round 9
// 187.398 us; speedup vs baseline: 1.0591x; 1.0591x over previous
//
#include <hip/hip_runtime.h>

#define BATCH 32
#define H 512
#define W 512
#define SEG 8                        // output rows per block
#define TPB 128                      // 2 waves; 4 cols/thread = full 512-col row
#define ROWF 528                     // 4 zero-pad + 512 + 4 zero-pad + 8 spare
#define NSTEP (SEG + 8)              // 16 row-enter steps
// final scalar = sum over pixels of ((1-cc1)+(1-cc2)) * 0.5 / (B*H*W)
#define SCALE (0.5f / 8388608.0f)

typedef float f32x4 __attribute__((ext_vector_type(4)));

// NO __launch_bounds__ min-waves arg: it spilled in r2 (88 MB) and r8 (31 MB).
__global__ __launch_bounds__(TPB) void ncc_loss_kernel(
    const float* __restrict__ g1, const float* __restrict__ g2,
    const float* __restrict__ gf, float* __restrict__ out)
{
    // [parity][enter/leave][image][528 floats]; pads give free h-halo
    __shared__ float sm[2][2][3][ROWF];

    const int t  = threadIdx.x;                  // owns cols 4t..4t+3
    const int y0 = blockIdx.y * SEG;
    const int b  = blockIdx.z;
    const size_t base = (size_t)b * (H * W);

    // zero the 24 pad-quarters once (covered by the first barrier)
    if (t < 24) {
        const int par = t & 1, wh = (t >> 1) & 1, q = t >> 2;
        *(f32x4*)&sm[par][wh][q % 3][(q / 3) ? 516 : 0] = 0.f;  // 16B aligned
    }

    const int voff = 16 * t;                     // own x4 byte offset in a row

    // prefetch one row's own-quarters into regs (bounds-checked loads;
    // vertical OOB rows get rec=0 -> all-zero row == conv zero padding)
    auto loadrow = [&](int yr, f32x4* M) {
        const int rec = ((unsigned)yr < (unsigned)H) ? (W * 4) : 0;
        const int yc  = yr < 0 ? 0 : (yr >= H ? H - 1 : yr);
        const size_t roff = base + (size_t)yc * W;
        __amdgpu_buffer_rsrc_t ra = __builtin_amdgcn_make_buffer_rsrc(
            (void*)(g1 + roff), (short)0, rec, 0x00020000);
        __amdgpu_buffer_rsrc_t rc = __builtin_amdgcn_make_buffer_rsrc(
            (void*)(g2 + roff), (short)0, rec, 0x00020000);
        __amdgpu_buffer_rsrc_t rv = __builtin_amdgcn_make_buffer_rsrc(
            (void*)(gf + roff), (short)0, rec, 0x00020000);
        M[0] = __builtin_bit_cast(f32x4, __builtin_amdgcn_raw_buffer_load_b128(ra, voff, 0, 0));
        M[1] = __builtin_bit_cast(f32x4, __builtin_amdgcn_raw_buffer_load_b128(rc, voff, 0, 0));
        M[2] = __builtin_bit_cast(f32x4, __builtin_amdgcn_raw_buffer_load_b128(rv, voff, 0, 0));
    };
    // commit prefetched regs to LDS (each line of the row staged exactly once)
    auto commit = [&](const f32x4* M, int par, int wh) {
        *(f32x4*)&sm[par][wh][0][4 + 4 * t] = M[0];   // byte 16+16t: aligned
        *(f32x4*)&sm[par][wh][1][4 + 4 * t] = M[1];
        *(f32x4*)&sm[par][wh][2][4 + 4 * t] = M[2];
    };

    // vertical running sums, 8 quantities x 4 columns
    float v1[4], v2[4], vf[4], v11[4], v22[4], vff[4], v1f[4], v2f[4];
#pragma unroll
    for (int c = 0; c < 4; ++c) {
        v1[c]=0.f; v2[c]=0.f; vf[c]=0.f; v11[c]=0.f;
        v22[c]=0.f; vff[c]=0.f; v1f[c]=0.f; v2f[c]=0.f;
    }
    float lsum = 0.f;
    const float inv_n = 1.0f / 81.0f;

    auto hwin = [](f32x4 L, f32x4 M, f32x4 R, float* h) {
        float s = (L[0]+L[1]) + (L[2]+L[3]) + ((M[0]+M[1]) + (M[2]+M[3])) + R[0];
        h[0]=s; s += R[1]-L[0]; h[1]=s; s += R[2]-L[1]; h[2]=s; s += R[3]-L[2]; h[3]=s;
    };
    auto hwinp = [](f32x4 UL, f32x4 UM, f32x4 UR,
                    f32x4 WL, f32x4 WM, f32x4 WR, float* h) {
        const float p0 = UL[0]*WL[0], p1 = UL[1]*WL[1], p2 = UL[2]*WL[2];
        float s = p0 + p1 + p2;
        s = fmaf(UL[3], WL[3], s);
        s = fmaf(UM[0], WM[0], s); s = fmaf(UM[1], WM[1], s);
        s = fmaf(UM[2], WM[2], s); s = fmaf(UM[3], WM[3], s);
        s = fmaf(UR[0], WR[0], s);
        h[0]=s;
        s = fmaf(UR[1], WR[1], s) - p0; h[1]=s;
        s = fmaf(UR[2], WR[2], s) - p1; h[2]=s;
        s = fmaf(UR[3], WR[3], s) - p2; h[3]=s;
    };

    // consume one staged row: L/R quarters from LDS (pads = zeros), M from regs.
    // Leave rows re-stage identical global bits -> bitwise-identical h-sums ->
    // exact cancellation (absmax 0 validated on this pattern in r6/r8).
    auto consume = [&](int par, int wh, const f32x4* M, float sg) {
        const float* p0 = &sm[par][wh][0][0];
        const float* p1 = &sm[par][wh][1][0];
        const float* p2 = &sm[par][wh][2][0];
        const f32x4 A0 = *(const f32x4*)(p0 + 4*t), A2 = *(const f32x4*)(p0 + 4*t + 8);
        const f32x4 C0 = *(const f32x4*)(p1 + 4*t), C2 = *(const f32x4*)(p1 + 4*t + 8);
        const f32x4 F0 = *(const f32x4*)(p2 + 4*t), F2 = *(const f32x4*)(p2 + 4*t + 8);
        float h[4];
        hwin(F0, M[2], F2, h);
#pragma unroll
        for (int c = 0; c < 4; ++c) vf[c]  = fmaf(sg, h[c], vf[c]);
        hwinp(F0, M[2], F2, F0, M[2], F2, h);
#pragma unroll
        for (int c = 0; c < 4; ++c) vff[c] = fmaf(sg, h[c], vff[c]);
        hwin(A0, M[0], A2, h);
#pragma unroll
        for (int c = 0; c < 4; ++c) v1[c]  = fmaf(sg, h[c], v1[c]);
        hwinp(A0, M[0], A2, A0, M[0], A2, h);
#pragma unroll
        for (int c = 0; c < 4; ++c) v11[c] = fmaf(sg, h[c], v11[c]);
        hwinp(A0, M[0], A2, F0, M[2], F2, h);
#pragma unroll
        for (int c = 0; c < 4; ++c) v1f[c] = fmaf(sg, h[c], v1f[c]);
        hwin(C0, M[1], C2, h);
#pragma unroll
        for (int c = 0; c < 4; ++c) v2[c]  = fmaf(sg, h[c], v2[c]);
        hwinp(C0, M[1], C2, C0, M[1], C2, h);
#pragma unroll
        for (int c = 0; c < 4; ++c) v22[c] = fmaf(sg, h[c], v22[c]);
        hwinp(C0, M[1], C2, F0, M[2], F2, h);
#pragma unroll
        for (int c = 0; c < 4; ++c) v2f[c] = fmaf(sg, h[c], v2f[c]);
    };

    auto emit = [&]() {
#pragma unroll
        for (int c = 0; c < 4; ++c) {
            const float u1 = v1[c]*inv_n, u2 = v2[c]*inv_n, uf = vf[c]*inv_n;
            const float cross1 = fmaf(-v1[c], uf, v1f[c]);
            const float var1   = fmaf(-v1[c], u1, v11[c]);
            const float varf   = fmaf(-vf[c], uf, vff[c]);
            const float cross2 = fmaf(-v2[c], uf, v2f[c]);
            const float var2   = fmaf(-v2[c], u2, v22[c]);
            const float d1 = fmaf(var1, varf, 1e-5f);
            const float d2 = fmaf(var2, varf, 1e-5f);
            const float inv = __builtin_amdgcn_rcpf(d1 * d2);
            float num = cross1 * cross1 * d2;
            num = fmaf(cross2 * cross2, d1, num);
            lsum += fmaf(-num, inv, 2.0f);
        }
    };

    // ---- pipelined step loop ----
    // step s: commit prefetched rows -> barrier -> issue prefetch for s+1
    //         (latency hidden by compute) -> consume s -> emit.
    // At each barrier no loads are outstanding, so the compiler's
    // vmcnt(0)-before-s_barrier drain costs nothing.
    f32x4 PE[2][3], PL[2][3];                    // prefetch double-buffers
    loadrow(y0 - 4, PE[0]);                      // prime the pipeline (s=0)

#pragma unroll 1
    for (int s = 0; s < NSTEP; ++s) {
        const int par = s & 1;
        const bool hasL = (s >= 9);              // uniform across the block
        commit(PE[par], par, 0);
        if (hasL) commit(PL[par], par, 1);
        __syncthreads();
        const int np = 1 - par;
        if (s + 1 < NSTEP) {
            loadrow(y0 - 3 + s, PE[np]);         // enter row for s+1
            if (s + 1 >= 9) loadrow(y0 + s - 12, PL[np]);  // leave row for s+1
        }
        consume(par, 0, PE[par], 1.0f);
        if (hasL) consume(par, 1, PL[par], -1.0f);
        if (s >= 8) emit();                      // output row y0 + (s-8)
    }

    // block reduction: 2 waves -> LDS -> one atomic
#pragma unroll
    for (int o = 32; o > 0; o >>= 1)
        lsum += __shfl_down(lsum, o, 64);
    __shared__ float wsum[2];
    if ((t & 63) == 0) wsum[t >> 6] = lsum;
    __syncthreads();
    if (t == 0) atomicAdd(out, (wsum[0] + wsum[1]) * SCALE);
}

extern "C" void kernel_launch(void* const* d_in, const int* in_sizes, int n_in,
                              void* d_out, int out_size, void* d_ws, size_t ws_size,
                              hipStream_t stream) {
    const float* img1 = (const float*)d_in[0];
    const float* img2 = (const float*)d_in[1];
    const float* fimg = (const float*)d_in[2];
    float* out = (float*)d_out;

    hipMemsetAsync(out, 0, sizeof(float), stream);  // d_out re-poisoned each call

    dim3 grid(1, H / SEG, BATCH);   // (1, 64, 32) = 2048 blocks x 2 waves
    ncc_loss_kernel<<<grid, dim3(TPB), 0, stream>>>(img1, img2, fimg, out);
}